// Round 1
// baseline (16165.125 us; speedup 1.0000x reference)
//
#include <hip/hip_runtime.h>
#include <math.h>

#define T_LEN 8192
#define NWG 4

// DPP helpers (ctrl must be literal): butterfly within rows of 16 lanes.
#define DPP_ADD(x, ctrl) ((x) + __int_as_float(__builtin_amdgcn_update_dpp(0, __float_as_int(x), (ctrl), 0xF, 0xF, true)))
#define DPP_MAX(x, ctrl) fmaxf((x), __int_as_float(__builtin_amdgcn_update_dpp(0, __float_as_int(x), (ctrl), 0xF, 0xF, true)))

// ---------------------------------------------------------------------------
// Kernel 1: pre = relu(embed_W[docs]) @ w_ih^T + (b_ih + b_hh)   (T x 1024)
// 64x64 tile, BK=16, 256 threads, 4x4 per thread.
// ---------------------------------------------------------------------------
__global__ __launch_bounds__(256, 4) void gemm_pre(
    const int* __restrict__ docs,
    const float* __restrict__ embW,
    const float* __restrict__ w_ih,
    const float* __restrict__ b_ih,
    const float* __restrict__ b_hh,
    float* __restrict__ pre)
{
    __shared__ __align__(16) float As[16][68];
    __shared__ __align__(16) float Bs[16][68];
    __shared__ int rowid[64];
    const int bt = blockIdx.x;   // 128 t-tiles
    const int bj = blockIdx.y;   // 16 j-tiles
    const int tid = threadIdx.x;
    if (tid < 64) rowid[tid] = docs[bt * 64 + tid];
    __syncthreads();
    const int ti = tid & 15, tj = tid >> 4;
    const int r = tid & 63;
    const int kk4 = (tid >> 6) * 4;
    float acc[4][4];
#pragma unroll
    for (int ii = 0; ii < 4; ++ii)
#pragma unroll
        for (int jj = 0; jj < 4; ++jj) acc[ii][jj] = 0.f;

    for (int k0 = 0; k0 < 256; k0 += 16) {
        float4 av = *(const float4*)(embW + (size_t)rowid[r] * 256 + k0 + kk4);
        float4 bv = *(const float4*)(w_ih + (size_t)(bj * 64 + r) * 256 + k0 + kk4);
        As[kk4 + 0][r] = fmaxf(av.x, 0.f);
        As[kk4 + 1][r] = fmaxf(av.y, 0.f);
        As[kk4 + 2][r] = fmaxf(av.z, 0.f);
        As[kk4 + 3][r] = fmaxf(av.w, 0.f);
        Bs[kk4 + 0][r] = bv.x;
        Bs[kk4 + 1][r] = bv.y;
        Bs[kk4 + 2][r] = bv.z;
        Bs[kk4 + 3][r] = bv.w;
        __syncthreads();
#pragma unroll
        for (int kk = 0; kk < 16; ++kk) {
            float4 a = *(const float4*)&As[kk][ti * 4];
            float4 b = *(const float4*)&Bs[kk][tj * 4];
            acc[0][0] += a.x * b.x; acc[0][1] += a.x * b.y; acc[0][2] += a.x * b.z; acc[0][3] += a.x * b.w;
            acc[1][0] += a.y * b.x; acc[1][1] += a.y * b.y; acc[1][2] += a.y * b.z; acc[1][3] += a.y * b.w;
            acc[2][0] += a.z * b.x; acc[2][1] += a.z * b.y; acc[2][2] += a.z * b.z; acc[2][3] += a.z * b.w;
            acc[3][0] += a.w * b.x; acc[3][1] += a.w * b.y; acc[3][2] += a.w * b.z; acc[3][3] += a.w * b.w;
        }
        __syncthreads();
    }
#pragma unroll
    for (int ii = 0; ii < 4; ++ii) {
        int t = bt * 64 + ti * 4 + ii;
#pragma unroll
        for (int jj = 0; jj < 4; ++jj) {
            int j = bj * 64 + tj * 4 + jj;
            pre[(size_t)t * 1024 + j] = acc[ii][jj] + b_ih[j] + b_hh[j];
        }
    }
}

// ---------------------------------------------------------------------------
// Kernel 2: sequential LSTM scan. 4 WGs x 512 threads.
// WG w owns hidden units [w*64, (w+1)*64) -> 256 gate rows, weights in VGPRs.
// Per step: partial dots + DPP reduce, 64 update lanes, device-scope barrier.
// ---------------------------------------------------------------------------
__global__ __launch_bounds__(512, 2) void lstm_scan(
    const float* __restrict__ pre,   // (T, 1024)
    const float* __restrict__ w_hh,  // (1024, 256)
    float* __restrict__ hs,          // (T, 256)
    float* __restrict__ syncf)       // [0]: counter; [64..]: hbuf[2][256]
{
    const int wgid = blockIdx.x;
    const int tid  = threadIdx.x;
    const int lane = tid & 63;
    const int wv   = tid >> 6;        // wave 0..7
    const int rs   = lane >> 4;       // row subgroup 0..3
    const int kq   = lane & 15;       // k-chunk 0..15

    unsigned* cnt = (unsigned*)syncf;
    float* hbuf = syncf + 64;

    // load weights: rows rho = wv*32 + rs*8 + r (r<8), k = [16*kq, 16*kq+16)
    float wreg[128];
#pragma unroll
    for (int rr = 0; rr < 8; ++rr) {
        int rho = wv * 32 + rs * 8 + rr;
        int grow = ((rho >> 6) * 256) + wgid * 64 + (rho & 63);
        const float* src = w_hh + (size_t)grow * 256 + kq * 16;
#pragma unroll
        for (int q = 0; q < 4; ++q) {
            float4 v = *(const float4*)(src + 4 * q);
            wreg[rr * 16 + 4 * q + 0] = v.x;
            wreg[rr * 16 + 4 * q + 1] = v.y;
            wreg[rr * 16 + 4 * q + 2] = v.z;
            wreg[rr * 16 + 4 * q + 3] = v.w;
        }
    }

    const bool is_writer = (kq < 8);
    const int rho_w = wv * 32 + rs * 8 + kq;           // valid when kq<8
    const int grow_w = ((rho_w >> 6) * 256) + wgid * 64 + (rho_w & 63);

    // h stored in 16 chunks of 16 f32, chunk stride 20 f32 (bank-spread, 16B aligned)
    __shared__ __align__(16) float sh_h[16 * 20];
    __shared__ float gate_lds[256];

    for (int i2 = tid; i2 < 16 * 20; i2 += 512) sh_h[i2] = 0.f;
    float c_reg = 0.f;

    float pre_cur = is_writer ? pre[grow_w] : 0.f;   // t = 0
    __syncthreads();

    for (int t = 0; t < T_LEN; ++t) {
        // ---- load my h chunk (16 values) ----
        float4 h0 = *(const float4*)&sh_h[kq * 20 + 0];
        float4 h1 = *(const float4*)&sh_h[kq * 20 + 4];
        float4 h2 = *(const float4*)&sh_h[kq * 20 + 8];
        float4 h3 = *(const float4*)&sh_h[kq * 20 + 12];
        float hv[16];
        hv[0]=h0.x; hv[1]=h0.y; hv[2]=h0.z; hv[3]=h0.w;
        hv[4]=h1.x; hv[5]=h1.y; hv[6]=h1.z; hv[7]=h1.w;
        hv[8]=h2.x; hv[9]=h2.y; hv[10]=h2.z; hv[11]=h2.w;
        hv[12]=h3.x; hv[13]=h3.y; hv[14]=h3.z; hv[15]=h3.w;

        // ---- partial dots + 16-lane butterfly reduce ----
        float acc0, acc1, acc2, acc3, acc4, acc5, acc6, acc7;
        {
            float a[8];
#pragma unroll
            for (int rr = 0; rr < 8; ++rr) {
                float s = 0.f;
#pragma unroll
                for (int j = 0; j < 16; ++j) s += wreg[rr * 16 + j] * hv[j];
                s = DPP_ADD(s, 0xB1);   // quad_perm [1,0,3,2]
                s = DPP_ADD(s, 0x4E);   // quad_perm [2,3,0,1]
                s = DPP_ADD(s, 0x141);  // row_half_mirror
                s = DPP_ADD(s, 0x140);  // row_mirror
                a[rr] = s;
            }
            acc0=a[0]; acc1=a[1]; acc2=a[2]; acc3=a[3];
            acc4=a[4]; acc5=a[5]; acc6=a[6]; acc7=a[7];
        }
        if (is_writer) {
            // select acc[kq] without dynamic register indexing
            float g = acc0;
            g = (kq == 1) ? acc1 : g;
            g = (kq == 2) ? acc2 : g;
            g = (kq == 3) ? acc3 : g;
            g = (kq == 4) ? acc4 : g;
            g = (kq == 5) ? acc5 : g;
            g = (kq == 6) ? acc6 : g;
            g = (kq == 7) ? acc7 : g;
            gate_lds[rho_w] = g + pre_cur;
            int tn = (t + 1 < T_LEN) ? (t + 1) : t;
            pre_cur = pre[(size_t)tn * 1024 + grow_w];   // prefetch next step
        }
        __syncthreads();

        // ---- cell update (64 lanes) + publish ----
        if (tid < 64) {
            float gi = gate_lds[tid];
            float gf = gate_lds[64 + tid];
            float gg = gate_lds[128 + tid];
            float go = gate_lds[192 + tid];
            float si = 1.f / (1.f + __expf(-gi));
            float sf = 1.f / (1.f + __expf(-gf));
            float tg = tanhf(gg);
            float so = 1.f / (1.f + __expf(-go));
            c_reg = sf * c_reg + si * tg;
            float h = so * tanhf(c_reg);
            hs[(size_t)t * 256 + wgid * 64 + tid] = h;
            __hip_atomic_store(&hbuf[(t & 1) * 256 + wgid * 64 + tid], h,
                               __ATOMIC_RELEASE, __HIP_MEMORY_SCOPE_AGENT);
        }
        __syncthreads();   // drains vmcnt: h stores visible at agent scope

        // ---- device barrier (monotonic counter) ----
        if (tid == 0) {
            __hip_atomic_fetch_add(cnt, 1u, __ATOMIC_RELEASE, __HIP_MEMORY_SCOPE_AGENT);
            unsigned tgt = (unsigned)NWG * (unsigned)(t + 1);
            while (__hip_atomic_load(cnt, __ATOMIC_ACQUIRE, __HIP_MEMORY_SCOPE_AGENT) < tgt) {}
        }
        __syncthreads();

        // ---- refresh full h into swizzled LDS ----
        if (tid < 256) {
            float hval = __hip_atomic_load(&hbuf[(t & 1) * 256 + tid],
                                           __ATOMIC_RELAXED, __HIP_MEMORY_SCOPE_AGENT);
            sh_h[(tid >> 4) * 20 + (tid & 15)] = hval;
        }
        __syncthreads();
    }
}

// ---------------------------------------------------------------------------
// Kernel 3: conv (FN=128, FL=5) over hs + per-block max over its 64 t's.
// 128 blocks x 256 threads; thread tile: 4 t's (strided 16) x 8 n's (strided 16).
// ---------------------------------------------------------------------------
__global__ __launch_bounds__(256) void conv_pool(
    const float* __restrict__ hs,    // (T, 256)
    const float* __restrict__ cw,    // (128, 1, 5, 256)
    const float* __restrict__ cb,    // (128,)
    float* __restrict__ part)        // (128 blocks, 128 n)
{
    __shared__ __align__(16) float hst[68 * 260];
    __shared__ __align__(16) float cwS[128 * 68];
    const int blk = blockIdx.x;
    const int t0 = blk * 64;
    const int tid = threadIdx.x;
    const int i = tid & 15;    // t-lane
    const int g = tid >> 4;    // n-group 0..15

    // load 68 rows of hs (clamped)
    for (int e = tid; e < 68 * 64; e += 256) {
        int rr = e >> 6;
        int c4 = (e & 63) * 4;
        int tg = t0 + rr; if (tg > 8191) tg = 8191;
        float4 v = *(const float4*)(hs + (size_t)tg * 256 + c4);
        *(float4*)&hst[rr * 260 + c4] = v;
    }

    float acc[4][8];
#pragma unroll
    for (int tt = 0; tt < 4; ++tt)
#pragma unroll
        for (int j = 0; j < 8; ++j) acc[tt][j] = 0.f;

    for (int l = 0; l < 5; ++l) {
        for (int hc = 0; hc < 4; ++hc) {
            __syncthreads();
            // stage cw chunk: n<128, h' in [hc*64, hc*64+64)
            {
                int n = tid >> 1;
                int hb = (tid & 1) * 32;
                const float* src = cw + (size_t)n * 1280 + l * 256 + hc * 64 + hb;
                float* dst = &cwS[n * 68 + hb];
#pragma unroll
                for (int q = 0; q < 8; ++q) {
                    float4 v = *(const float4*)(src + 4 * q);
                    *(float4*)(dst + 4 * q) = v;
                }
            }
            __syncthreads();
#pragma unroll 4
            for (int q = 0; q < 16; ++q) {
                float4 hvv[4];
#pragma unroll
                for (int tt = 0; tt < 4; ++tt)
                    hvv[tt] = *(const float4*)&hst[(i + 16 * tt + l) * 260 + hc * 64 + 4 * q];
#pragma unroll
                for (int j = 0; j < 8; ++j) {
                    float4 wv = *(const float4*)&cwS[(g + 16 * j) * 68 + 4 * q];
#pragma unroll
                    for (int tt = 0; tt < 4; ++tt) {
                        acc[tt][j] += hvv[tt].x * wv.x + hvv[tt].y * wv.y
                                    + hvv[tt].z * wv.z + hvv[tt].w * wv.w;
                    }
                }
            }
        }
    }

    // bias, mask t>=8188, per-thread max over tt, DPP max over 16 i-lanes
    float m[8];
#pragma unroll
    for (int j = 0; j < 8; ++j) {
        int n = g + 16 * j;
        float cbn = cb[n];
        float mm = -INFINITY;
#pragma unroll
        for (int tt = 0; tt < 4; ++tt) {
            int t = t0 + i + 16 * tt;
            float v = acc[tt][j] + cbn;
            if (t < 8188) mm = fmaxf(mm, v);
        }
        mm = DPP_MAX(mm, 0xB1);
        mm = DPP_MAX(mm, 0x4E);
        mm = DPP_MAX(mm, 0x141);
        mm = DPP_MAX(mm, 0x140);
        m[j] = mm;
    }
    if (i == 0) {
#pragma unroll
        for (int j = 0; j < 8; ++j)
            part[(size_t)blk * 128 + g + 16 * j] = m[j];
    }
}

// ---------------------------------------------------------------------------
// Kernel 4: final head — pool-reduce, logits, log_softmax, loss + acc.
// ---------------------------------------------------------------------------
__global__ void final_head(
    const float* __restrict__ part,      // (128, 128)
    const float* __restrict__ logits_w,  // (20, 128)
    const float* __restrict__ logits_b,  // (20,)
    const int* __restrict__ labels,
    float* __restrict__ out)             // [loss, acc]
{
    __shared__ float pooled[128];
    __shared__ float lgt[20];
    int tid = threadIdx.x;  // 128 threads
    float mx = -INFINITY;
    for (int b = 0; b < 128; ++b) mx = fmaxf(mx, part[(size_t)b * 128 + tid]);
    pooled[tid] = mx;
    __syncthreads();
    if (tid < 20) {
        float s = logits_b[tid];
        for (int k = 0; k < 128; ++k) s += logits_w[tid * 128 + k] * pooled[k];
        lgt[tid] = s;
    }
    __syncthreads();
    if (tid == 0) {
        float m = lgt[0]; int am = 0;
        for (int c2 = 1; c2 < 20; ++c2) { if (lgt[c2] > m) { m = lgt[c2]; am = c2; } }
        float se = 0.f;
        for (int c2 = 0; c2 < 20; ++c2) se += expf(lgt[c2] - m);
        float lse = m + logf(se);
        int lbl = labels[0];
        out[0] = -(lgt[lbl] - lse);
        out[1] = (am == lbl) ? 1.f : 0.f;
    }
}

// ---------------------------------------------------------------------------
extern "C" void kernel_launch(void* const* d_in, const int* in_sizes, int n_in,
                              void* d_out, int out_size, void* d_ws, size_t ws_size,
                              hipStream_t stream) {
    (void)in_sizes; (void)n_in; (void)out_size; (void)ws_size;
    const int*   docs   = (const int*)d_in[0];
    const int*   labels = (const int*)d_in[2];
    const float* embW   = (const float*)d_in[4];
    const float* w_ih   = (const float*)d_in[5];
    const float* w_hh   = (const float*)d_in[6];
    const float* b_ih   = (const float*)d_in[7];
    const float* b_hh   = (const float*)d_in[8];
    const float* cw     = (const float*)d_in[9];
    const float* cb     = (const float*)d_in[10];
    const float* lw     = (const float*)d_in[11];
    const float* lb     = (const float*)d_in[12];
    float* out = (float*)d_out;

    char* ws = (char*)d_ws;
    float* pre   = (float*)(ws);                       // 8192*1024*4 = 33554432
    float* hs    = (float*)(ws + 33554432);            // 8192*256*4  =  8388608
    float* part  = (float*)(ws + 41943040);            // 128*128*4   =    65536
    float* syncf = (float*)(ws + 42008576);            // counter + hbuf

    hipMemsetAsync(ws + 42008576, 0, 4096, stream);
    gemm_pre<<<dim3(128, 16, 1), 256, 0, stream>>>(docs, embW, w_ih, b_ih, b_hh, pre);
    lstm_scan<<<NWG, 512, 0, stream>>>(pre, w_hh, hs, syncf);
    conv_pool<<<128, 256, 0, stream>>>(hs, cw, cb, part);
    final_head<<<1, 128, 0, stream>>>(part, lw, lb, labels, out);
}